// Round 1
// baseline (115.937 us; speedup 1.0000x reference)
//
#include <hip/hip_runtime.h>

#define NCLS 80
#define NBOX 32
#define CHUNK 64
#define FEPS 1e-4f

__global__ __launch_bounds__(256) void focal_main(
    const float* __restrict__ cls,      // (B, A, 80)
    const float* __restrict__ reg,      // (B, A, 4)
    const float* __restrict__ anchors,  // (A, 4)  [y1,x1,y2,x2]
    const float* __restrict__ ann,      // (B, 32, 5) [x1,y1,x2,y2,label]
    double* __restrict__ cls_sum,       // [B]
    double* __restrict__ reg_sum,       // [B]
    unsigned int* __restrict__ pos_cnt, // [B]
    int A, int chunks_per_img)
{
    __shared__ float s_ann[NBOX * 5];
    __shared__ int   s_code[CHUNK];
    __shared__ float s_wsum[4];

    const int blk   = blockIdx.x;
    const int b     = blk / chunks_per_img;
    const int chunk = blk % chunks_per_img;
    const int base  = chunk * CHUNK;
    const int nvalid = min(CHUNK, A - base);
    const int tid = threadIdx.x;

    if (tid < NBOX * 5) s_ann[tid] = ann[(size_t)b * NBOX * 5 + tid];
    __syncthreads();

    // ---- phase 1: per-anchor IoU / code / regression loss (wave 0 only) ----
    if (tid < CHUNK) {
        float reg_part = 0.f;
        int   pos_part = 0;
        int   code = -2;   // -2 = ignore, -1 = negative, >=0 = positive label
        const int a = base + tid;
        if (a < A) {
            float4 an = *(const float4*)(anchors + (size_t)a * 4);
            const float ya1 = an.x, xa1 = an.y, ya2 = an.z, xa2 = an.w;
            const float area_a = (xa2 - xa1) * (ya2 - ya1);
            float best = -1.f; int arg = 0;
            #pragma unroll
            for (int m = 0; m < NBOX; ++m) {
                const float xb1 = s_ann[m*5+0], yb1 = s_ann[m*5+1];
                const float xb2 = s_ann[m*5+2], yb2 = s_ann[m*5+3];
                float iw = fminf(xa2, xb2) - fmaxf(xa1, xb1); iw = fmaxf(iw, 0.f);
                float ih = fminf(ya2, yb2) - fmaxf(ya1, yb1); ih = fmaxf(ih, 0.f);
                const float inter  = iw * ih;
                const float area_b = (xb2 - xb1) * (yb2 - yb1);
                const float iou = inter / (area_a + area_b - inter);
                if (iou > best) { best = iou; arg = m; }  // first-max = jnp.argmax
            }
            if (best >= 0.5f) {
                code = (int)s_ann[arg*5 + 4];
                const float bx1 = s_ann[arg*5+0], by1 = s_ann[arg*5+1];
                const float bx2 = s_ann[arg*5+2], by2 = s_ann[arg*5+3];
                float g_w = bx2 - bx1, g_h = by2 - by1;
                const float g_cx = bx1 + 0.5f * g_w, g_cy = by1 + 0.5f * g_h;
                g_w = fmaxf(g_w, 1.f); g_h = fmaxf(g_h, 1.f);
                const float a_w = xa2 - xa1, a_h = ya2 - ya1;
                const float a_cx = xa1 + 0.5f * a_w, a_cy = ya1 + 0.5f * a_h;
                const float t0 = (g_cy - a_cy) / a_h;   // tdy
                const float t1 = (g_cx - a_cx) / a_w;   // tdx
                const float t2 = __logf(g_h / a_h);     // tdh
                const float t3 = __logf(g_w / a_w);     // tdw
                const float4 rg = *(const float4*)(reg + ((size_t)b * A + a) * 4);
                const float d[4] = { fabsf(t0 - rg.x), fabsf(t1 - rg.y),
                                     fabsf(t2 - rg.z), fabsf(t3 - rg.w) };
                const float TH = 1.f/9.f, HB = 0.5f/9.f;
                #pragma unroll
                for (int k = 0; k < 4; ++k)
                    reg_part += (d[k] <= TH) ? 4.5f * d[k] * d[k] : d[k] - HB;
                pos_part = 1;
            } else if (best < 0.4f) {
                code = -1;
            }
        }
        s_code[tid] = code;
        // reduce within wave 0 (tids 0..63 are exactly one wave)
        #pragma unroll
        for (int off = 32; off; off >>= 1) {
            reg_part += __shfl_down(reg_part, off, 64);
            pos_part += __shfl_down(pos_part, off, 64);
        }
        if (tid == 0) {
            if (reg_part != 0.f) atomicAdd(&reg_sum[b], (double)reg_part);
            if (pos_part)        atomicAdd(&pos_cnt[b], (unsigned int)pos_part);
        }
    }
    __syncthreads();

    // ---- phase 2: classification focal loss, coalesced float4 stream ----
    const float4* cbase = (const float4*)(cls + ((size_t)b * A + base) * NCLS);
    const int nq = nvalid * (NCLS / 4);
    float csum = 0.f;
    for (int j = tid; j < nq; j += 256) {
        const int al = j / (NCLS / 4);
        const int cq = j % (NCLS / 4);
        const int code = s_code[al];
        const float4 v = cbase[j];
        if (code != -2) {
            const float cc[4] = { v.x, v.y, v.z, v.w };
            #pragma unroll
            for (int k = 0; k < 4; ++k) {
                float c = fminf(fmaxf(cc[k], FEPS), 1.f - FEPS);
                const bool ispos = (code == cq * 4 + k);
                const float p     = ispos ? (1.f - c) : c;
                const float alpha = ispos ? 0.25f : 0.75f;
                // pos: 0.25*(1-c)^2*(-log c); neg: 0.75*c^2*(-log(1-c))
                csum += alpha * p * p * (-__logf(1.f - p));
            }
        }
    }
    #pragma unroll
    for (int off = 32; off; off >>= 1) csum += __shfl_down(csum, off, 64);
    if ((tid & 63) == 0) s_wsum[tid >> 6] = csum;
    __syncthreads();
    if (tid == 0) {
        const float tot = s_wsum[0] + s_wsum[1] + s_wsum[2] + s_wsum[3];
        atomicAdd(&cls_sum[b], (double)tot);
    }
}

__global__ void focal_finalize(const double* __restrict__ cls_sum,
                               const double* __restrict__ reg_sum,
                               const unsigned int* __restrict__ pos_cnt,
                               float* __restrict__ out, int B)
{
    if (threadIdx.x == 0 && blockIdx.x == 0) {
        double cm = 0.0, rm = 0.0;
        for (int b = 0; b < B; ++b) {
            const double np = (double)pos_cnt[b];
            cm += cls_sum[b] / fmax(np, 1.0);
            rm += (np > 0.0) ? reg_sum[b] / fmax(np * 4.0, 1.0) : 0.0;
        }
        out[0] = (float)(cm / B);
        out[1] = (float)(rm / B);
    }
}

extern "C" void kernel_launch(void* const* d_in, const int* in_sizes, int n_in,
                              void* d_out, int out_size, void* d_ws, size_t ws_size,
                              hipStream_t stream) {
    const float* cls     = (const float*)d_in[0];
    const float* reg     = (const float*)d_in[1];
    const float* anchors = (const float*)d_in[2];
    const float* ann     = (const float*)d_in[3];
    float* out = (float*)d_out;

    const int A = in_sizes[2] / 4;             // anchors: (1, A, 4)
    const int B = in_sizes[1] / (A * 4);       // regressions: (B, A, 4)

    // workspace: [B] double cls_sum | [B] double reg_sum | [B] uint pos_cnt
    double* cls_sum = (double*)d_ws;
    double* reg_sum = cls_sum + B;
    unsigned int* pos_cnt = (unsigned int*)(reg_sum + B);
    const size_t acc_bytes = (size_t)B * (8 + 8 + 4);
    hipMemsetAsync(d_ws, 0, acc_bytes, stream);

    const int chunks_per_img = (A + CHUNK - 1) / CHUNK;
    const int nblocks = B * chunks_per_img;
    focal_main<<<nblocks, 256, 0, stream>>>(cls, reg, anchors, ann,
                                            cls_sum, reg_sum, pos_cnt,
                                            A, chunks_per_img);
    focal_finalize<<<1, 64, 0, stream>>>(cls_sum, reg_sum, pos_cnt, out, B);
}

// Round 2
// 52.551 us; speedup vs baseline: 2.2062x; 2.2062x over previous
//
#include <hip/hip_runtime.h>

#define NCLS 80
#define NQ   20            // float4 quads per anchor (80/4)
#define NBOX 32
#define CHUNK 256          // anchors per block == blockDim.x
#define CLO 1e-4f
#define CHI 0.9999f

__global__ __launch_bounds__(256) void focal_main(
    const float* __restrict__ cls,      // (B, A, 80)
    const float* __restrict__ reg,      // (B, A, 4)
    const float* __restrict__ anchors,  // (A, 4)  [y1,x1,y2,x2]
    const float* __restrict__ ann,      // (B, 32, 5) [x1,y1,x2,y2,label]
    double* __restrict__ cls_sum,       // [B]
    double* __restrict__ reg_sum,       // [B]
    float* __restrict__ pos_cnt,        // [B]
    int A, int chunks_per_img)
{
    __shared__ float4 s_box[NBOX];      // x1,y1,x2,y2
    __shared__ float  s_area[NBOX];
    __shared__ float  s_label[NBOX];
    __shared__ float  s_mask[CHUNK];    // 1 = not ignored, 0 = ignored/invalid
    __shared__ float  s_red[4][4];

    const int b     = blockIdx.x / chunks_per_img;
    const int chunk = blockIdx.x % chunks_per_img;
    const int base  = chunk * CHUNK;
    const int tid   = threadIdx.x;
    const int nv    = min(CHUNK, A - base);

    if (tid < NBOX) {
        const float* p = ann + (size_t)b * NBOX * 5 + tid * 5;
        const float4 bx = make_float4(p[0], p[1], p[2], p[3]);
        s_box[tid]   = bx;
        s_area[tid]  = (bx.z - bx.x) * (bx.w - bx.y);
        s_label[tid] = p[4];
    }
    __syncthreads();

    // ---- phase 1: one anchor per thread (all 4 waves active) ----
    float reg_acc = 0.f, pos_acc = 0.f, corr = 0.f, mask = 0.f;
    const int a = base + tid;
    if (tid < nv) {
        const float4 an = *(const float4*)(anchors + (size_t)a * 4);
        const float ya1 = an.x, xa1 = an.y, ya2 = an.z, xa2 = an.w;
        const float area_a = (xa2 - xa1) * (ya2 - ya1);

        // division-free argmax over (inter, union) pairs
        float4 b0 = s_box[0];
        float iw = fmaxf(fminf(xa2, b0.z) - fmaxf(xa1, b0.x), 0.f);
        float ih = fmaxf(fminf(ya2, b0.w) - fmaxf(ya1, b0.y), 0.f);
        float ib = iw * ih;
        float ub = area_a + s_area[0] - ib;
        int   arg = 0;
        #pragma unroll
        for (int m = 1; m < NBOX; ++m) {
            const float4 bm = s_box[m];
            iw = fmaxf(fminf(xa2, bm.z) - fmaxf(xa1, bm.x), 0.f);
            ih = fmaxf(fminf(ya2, bm.w) - fmaxf(ya1, bm.y), 0.f);
            const float im = iw * ih;
            const float um = area_a + s_area[m] - im;
            const bool gt = (im * ub) > (ib * um);   // iou_m > iou_best
            ib  = gt ? im : ib;
            ub  = gt ? um : ub;
            arg = gt ? m  : arg;
        }
        const float iou_max = ib / ub;   // single exact divide for thresholds

        if (iou_max >= 0.5f) {
            pos_acc = 1.f; mask = 1.f;
            const float4 bb = s_box[arg];
            // ---- positive-class correction for phase 2's all-negative sum
            const int L = (int)s_label[arg];
            float c = cls[((size_t)b * A + a) * NCLS + L];
            c = fminf(fmaxf(c, CLO), CHI);
            corr = 0.25f * (1.f - c) * (1.f - c) * (-__logf(c))
                 - 0.75f * c * c * (-__logf(1.f - c));
            // ---- regression smooth L1
            float gw = bb.z - bb.x, gh = bb.w - bb.y;
            const float gcx = bb.x + 0.5f * gw, gcy = bb.y + 0.5f * gh;
            gw = fmaxf(gw, 1.f); gh = fmaxf(gh, 1.f);
            const float aw = xa2 - xa1, ah = ya2 - ya1;
            const float acx = xa1 + 0.5f * aw, acy = ya1 + 0.5f * ah;
            const float t0 = (gcy - acy) / ah;   // tdy
            const float t1 = (gcx - acx) / aw;   // tdx
            const float t2 = __logf(gh / ah);    // tdh
            const float t3 = __logf(gw / aw);    // tdw
            const float4 rg = *(const float4*)(reg + ((size_t)b * A + a) * 4);
            const float d[4] = { fabsf(t0 - rg.x), fabsf(t1 - rg.y),
                                 fabsf(t2 - rg.z), fabsf(t3 - rg.w) };
            const float TH = 1.f / 9.f, HB = 0.5f / 9.f;
            #pragma unroll
            for (int k = 0; k < 4; ++k)
                reg_acc += (d[k] <= TH) ? 4.5f * d[k] * d[k] : d[k] - HB;
        } else if (iou_max < 0.4f) {
            mask = 1.f;          // negative: all classes in neg-form sum
        }                        // else: ignore band, mask stays 0
    }
    s_mask[tid] = mask;
    __syncthreads();

    // ---- phase 2: stream 256 anchors x 80 cls, all-negative focal form ----
    // element contribution (target != 1): 0.75 * c^2 * (-ln(1-c))
    //   accumulate S = sum c^2 * log2(1-c); final scale by -0.75*ln2
    float S = 0.f;
    const float4* cbase = (const float4*)(cls + ((size_t)b * A + base) * NCLS);
    if (nv == CHUNK) {
        #pragma unroll 5
        for (int i = 0; i < NQ; ++i) {
            const int j  = tid + (i << 8);
            const int al = (int)((unsigned)j / 20u);
            const float m = s_mask[al];
            const float4 v = cbase[j];
            float q = 0.f;
            {
                float c = fminf(fmaxf(v.x, CLO), CHI);
                q = fmaf(c * c, __log2f(1.f - c), q);
                c = fminf(fmaxf(v.y, CLO), CHI);
                q = fmaf(c * c, __log2f(1.f - c), q);
                c = fminf(fmaxf(v.z, CLO), CHI);
                q = fmaf(c * c, __log2f(1.f - c), q);
                c = fminf(fmaxf(v.w, CLO), CHI);
                q = fmaf(c * c, __log2f(1.f - c), q);
            }
            S = fmaf(m, q, S);
        }
    } else {
        for (int i = 0; i < NQ; ++i) {
            const int j  = tid + (i << 8);
            const int al = (int)((unsigned)j / 20u);
            if (al < nv) {
                const float m = s_mask[al];
                const float4 v = cbase[j];
                float q = 0.f;
                float c = fminf(fmaxf(v.x, CLO), CHI);
                q = fmaf(c * c, __log2f(1.f - c), q);
                c = fminf(fmaxf(v.y, CLO), CHI);
                q = fmaf(c * c, __log2f(1.f - c), q);
                c = fminf(fmaxf(v.z, CLO), CHI);
                q = fmaf(c * c, __log2f(1.f - c), q);
                c = fminf(fmaxf(v.w, CLO), CHI);
                q = fmaf(c * c, __log2f(1.f - c), q);
                S = fmaf(m, q, S);
            }
        }
    }

    // ---- block reduction: S, corr, reg_acc, pos_acc ----
    #pragma unroll
    for (int off = 32; off; off >>= 1) {
        S       += __shfl_xor(S,       off, 64);
        corr    += __shfl_xor(corr,    off, 64);
        reg_acc += __shfl_xor(reg_acc, off, 64);
        pos_acc += __shfl_xor(pos_acc, off, 64);
    }
    if ((tid & 63) == 0) {
        const int w = tid >> 6;
        s_red[w][0] = S; s_red[w][1] = corr;
        s_red[w][2] = reg_acc; s_red[w][3] = pos_acc;
    }
    __syncthreads();
    if (tid == 0) {
        float St = 0.f, Ct = 0.f, Rt = 0.f, Pt = 0.f;
        #pragma unroll
        for (int w = 0; w < 4; ++w) {
            St += s_red[w][0]; Ct += s_red[w][1];
            Rt += s_red[w][2]; Pt += s_red[w][3];
        }
        const double clsv = (double)Ct
                          - 0.75 * 0.6931471805599453 * (double)St;
        atomicAdd(&cls_sum[b], clsv);
        if (Rt != 0.f) atomicAdd(&reg_sum[b], (double)Rt);
        if (Pt != 0.f) atomicAdd(&pos_cnt[b], Pt);
    }
}

__global__ void focal_finalize(const double* __restrict__ cls_sum,
                               const double* __restrict__ reg_sum,
                               const float* __restrict__ pos_cnt,
                               float* __restrict__ out, int B)
{
    if (threadIdx.x == 0 && blockIdx.x == 0) {
        double cm = 0.0, rm = 0.0;
        for (int b = 0; b < B; ++b) {
            const double np = (double)pos_cnt[b];
            cm += cls_sum[b] / fmax(np, 1.0);
            rm += (np > 0.0) ? reg_sum[b] / fmax(np * 4.0, 1.0) : 0.0;
        }
        out[0] = (float)(cm / B);
        out[1] = (float)(rm / B);
    }
}

extern "C" void kernel_launch(void* const* d_in, const int* in_sizes, int n_in,
                              void* d_out, int out_size, void* d_ws, size_t ws_size,
                              hipStream_t stream) {
    const float* cls     = (const float*)d_in[0];
    const float* reg     = (const float*)d_in[1];
    const float* anchors = (const float*)d_in[2];
    const float* ann     = (const float*)d_in[3];
    float* out = (float*)d_out;

    const int A = in_sizes[2] / 4;             // anchors: (1, A, 4)
    const int B = in_sizes[1] / (A * 4);       // regressions: (B, A, 4)

    double* cls_sum = (double*)d_ws;
    double* reg_sum = cls_sum + B;
    float*  pos_cnt = (float*)(reg_sum + B);
    hipMemsetAsync(d_ws, 0, (size_t)B * (8 + 8 + 4), stream);

    const int chunks_per_img = (A + CHUNK - 1) / CHUNK;
    const int nblocks = B * chunks_per_img;
    focal_main<<<nblocks, 256, 0, stream>>>(cls, reg, anchors, ann,
                                            cls_sum, reg_sum, pos_cnt,
                                            A, chunks_per_img);
    focal_finalize<<<1, 64, 0, stream>>>(cls_sum, reg_sum, pos_cnt, out, B);
}